// Round 1
// baseline (986.048 us; speedup 1.0000x reference)
//
#include <hip/hip_runtime.h>
#include <hip/hip_bf16.h>
#include <cmath>

// Problem constants
#define B_  32
#define N_  1024
#define DV_ 512
#define L_  256
#define S_  8
#define DT_ 512
#define VOCAB_ 1024
#define BAND_ 16

// ---------------------------------------------------------------------------
// K1: per (b,l): gather emb rows, depthwise conv (k=3, SAME, cross-corr),
// silu, mean over s -> shm[bl][c]; also meanE -> mbuf[bl][c]
// ---------------------------------------------------------------------------
__global__ __launch_bounds__(256) void text_front(
    const int* __restrict__ ids, const float* __restrict__ emb,
    const float* __restrict__ dwk, float* __restrict__ shm,
    float* __restrict__ mbuf) {
  int bl = blockIdx.x;
  int tid = threadIdx.x;
  __shared__ int sid[S_];
  if (tid < S_) sid[tid] = ids[bl * S_ + tid];
  __syncthreads();
  for (int c = tid; c < DT_; c += 256) {
    float x[S_];
#pragma unroll
    for (int s = 0; s < S_; ++s) x[s] = emb[(size_t)sid[s] * DT_ + c];
    float k0 = dwk[c * 3 + 0], k1 = dwk[c * 3 + 1], k2 = dwk[c * 3 + 2];
    float me = 0.f, sh = 0.f;
#pragma unroll
    for (int s = 0; s < S_; ++s) {
      float xm = (s > 0) ? x[s - 1] : 0.0f;
      float xp = (s < S_ - 1) ? x[s + 1] : 0.0f;
      float h = k0 * xm + k1 * x[s] + k2 * xp;
      float si = h / (1.0f + expf(-h));  // silu
      me += x[s];
      sh += si;
    }
    shm[(size_t)bl * DT_ + c] = sh * (1.0f / S_);
    mbuf[(size_t)bl * DT_ + c] = me * (1.0f / S_);
  }
}

// ---------------------------------------------------------------------------
// Generic f32 GEMM: C[m][n] (+)= sum_k A[m][k] * B[n][k]
// A:[M,K] row-major, B:[N,K] row-major (i.e. X @ W.T with W=[out,in]).
// Tile 128x64, BK=16, 256 threads, 8x4 per thread.
// Requires M%128==0, N%64==0, K%16==0.
// ---------------------------------------------------------------------------
template <bool ACC>
__global__ __launch_bounds__(256) void gemm_abt(
    const float* __restrict__ A, const float* __restrict__ B,
    float* __restrict__ C, int M, int N, int K) {
  __shared__ float As[16][132];
  __shared__ float Bs[16][68];
  int tid = threadIdx.x;
  int tx = tid & 15;   // col group (TN=4) -> 64 cols
  int ty = tid >> 4;   // row group (TM=8) -> 128 rows
  int bm = blockIdx.y * 128, bn = blockIdx.x * 64;
  int lr = tid >> 2;         // 0..63
  int lk = (tid & 3) << 2;   // 0,4,8,12
  const float* Ap = A + (size_t)(bm + lr) * K + lk;
  const float* Ap2 = Ap + (size_t)64 * K;
  const float* Bp = B + (size_t)(bn + lr) * K + lk;
  float acc[8][4] = {};
  for (int k0 = 0; k0 < K; k0 += 16) {
    float4 a1 = *(const float4*)(Ap + k0);
    float4 a2 = *(const float4*)(Ap2 + k0);
    float4 b1 = *(const float4*)(Bp + k0);
    As[lk + 0][lr] = a1.x; As[lk + 1][lr] = a1.y;
    As[lk + 2][lr] = a1.z; As[lk + 3][lr] = a1.w;
    As[lk + 0][lr + 64] = a2.x; As[lk + 1][lr + 64] = a2.y;
    As[lk + 2][lr + 64] = a2.z; As[lk + 3][lr + 64] = a2.w;
    Bs[lk + 0][lr] = b1.x; Bs[lk + 1][lr] = b1.y;
    Bs[lk + 2][lr] = b1.z; Bs[lk + 3][lr] = b1.w;
    __syncthreads();
#pragma unroll
    for (int kk = 0; kk < 16; ++kk) {
      float4 av0 = *(const float4*)&As[kk][ty * 8];
      float4 av1 = *(const float4*)&As[kk][ty * 8 + 4];
      float4 bv = *(const float4*)&Bs[kk][tx * 4];
      float a_[8] = {av0.x, av0.y, av0.z, av0.w, av1.x, av1.y, av1.z, av1.w};
      float b_[4] = {bv.x, bv.y, bv.z, bv.w};
#pragma unroll
      for (int i = 0; i < 8; ++i)
#pragma unroll
        for (int j = 0; j < 4; ++j) acc[i][j] += a_[i] * b_[j];
    }
    __syncthreads();
  }
#pragma unroll
  for (int i = 0; i < 8; ++i) {
    int row = bm + ty * 8 + i;
    float4* cp = (float4*)(C + (size_t)row * N + bn + tx * 4);
    float4 v = make_float4(acc[i][0], acc[i][1], acc[i][2], acc[i][3]);
    if (ACC) {
      float4 o = *cp;
      v.x += o.x; v.y += o.y; v.z += o.z; v.w += o.w;
    }
    *cp = v;
  }
}

// ---------------------------------------------------------------------------
// K3: LayerNorm over DT=512 per row
// ---------------------------------------------------------------------------
__global__ __launch_bounds__(256) void ln_kernel(
    const float* __restrict__ m, const float* __restrict__ g,
    const float* __restrict__ bta, float* __restrict__ q) {
  int row = blockIdx.x;
  int tid = threadIdx.x;
  float v0 = m[(size_t)row * 512 + tid];
  float v1 = m[(size_t)row * 512 + 256 + tid];
  __shared__ float red[4], red2[4];
  float s = v0 + v1;
#pragma unroll
  for (int d = 32; d; d >>= 1) s += __shfl_xor(s, d);
  if ((tid & 63) == 0) red[tid >> 6] = s;
  __syncthreads();
  float mu = (red[0] + red[1] + red[2] + red[3]) * (1.0f / 512.0f);
  float d0 = v0 - mu, d1 = v1 - mu;
  float s2 = d0 * d0 + d1 * d1;
#pragma unroll
  for (int d = 32; d; d >>= 1) s2 += __shfl_xor(s2, d);
  if ((tid & 63) == 0) red2[tid >> 6] = s2;
  __syncthreads();
  float var = (red2[0] + red2[1] + red2[2] + red2[3]) * (1.0f / 512.0f);
  float r = rsqrtf(var + 1e-5f);
  q[(size_t)row * 512 + tid] = d0 * r * g[tid] + bta[tid];
  q[(size_t)row * 512 + 256 + tid] = d1 * r * g[tid + 256] + bta[tid + 256];
}

// ---------------------------------------------------------------------------
// K7: banded attention. One block per (b,l). center = floor(1023*l/255),
// band |idx-center|<=16. logits = Q.K/sqrt(512) + alpha*(c-idx)/16.000001.
// Softmax over band; writes full A row (zeros outside), Fv = A @ V (band only).
// ---------------------------------------------------------------------------
__global__ __launch_bounds__(256) void attn_kernel(
    const float* __restrict__ Q, const float* __restrict__ Kb,
    const float* __restrict__ Vb, const float* __restrict__ alpha_p,
    float* __restrict__ A, float* __restrict__ Fv) {
  int bl = blockIdx.x;
  int b = bl >> 8, l = bl & 255;
  int tid = threadIdx.x;
  int c = (1023 * l) / 255;
  int lo = max(0, c - BAND_), hi = min(N_ - 1, c + BAND_);
  int W = hi - lo + 1;  // <= 33
  __shared__ float qs[512];
  __shared__ float logit[33];
  __shared__ float av[33];
  qs[tid] = Q[(size_t)bl * 512 + tid];
  qs[tid + 256] = Q[(size_t)bl * 512 + 256 + tid];
  __syncthreads();
  int wv = tid >> 6, lane = tid & 63;
  const float4* q4 = (const float4*)qs;
  for (int j = wv; j < W; j += 4) {
    const float4* krow = (const float4*)(Kb + ((size_t)(b * N_ + lo + j)) * 512);
    float4 k1 = krow[lane], k2 = krow[lane + 64];
    float4 q1 = q4[lane], q2 = q4[lane + 64];
    float s = k1.x * q1.x + k1.y * q1.y + k1.z * q1.z + k1.w * q1.w +
              k2.x * q2.x + k2.y * q2.y + k2.z * q2.z + k2.w * q2.w;
#pragma unroll
    for (int d = 32; d; d >>= 1) s += __shfl_down(s, d);
    if (lane == 0) logit[j] = s;
  }
  __syncthreads();
  if (tid < 64) {
    float al = *alpha_p;
    float x = -INFINITY;
    if (tid < W) {
      float dirv = al * ((float)(c - (lo + tid)) / 16.000001f);
      x = logit[tid] * 0.044194173824159216f + dirv;  // * 512^-0.5
    }
    float mx = x;
#pragma unroll
    for (int d = 32; d; d >>= 1) mx = fmaxf(mx, __shfl_xor(mx, d));
    float e = (tid < W) ? expf(x - mx) : 0.0f;
    float sm = e;
#pragma unroll
    for (int d = 32; d; d >>= 1) sm += __shfl_xor(sm, d);
    if (tid < W) av[tid] = e / sm;
  }
  __syncthreads();
  // full A row (zeros outside band)
  float* Arow = A + (size_t)bl * N_;
#pragma unroll
  for (int p = tid; p < N_; p += 256) {
    Arow[p] = (p >= lo && p <= hi) ? av[p - lo] : 0.0f;
  }
  // Fv = sum_j a[j] * V[row j]
  float* fr = Fv + (size_t)bl * 512;
  for (int ch = tid; ch < 512; ch += 256) {
    float acc = 0.f;
    for (int j = 0; j < W; ++j)
      acc += av[j] * Vb[((size_t)(b * N_ + lo + j)) * 512 + ch];
    fr[ch] = acc;
  }
}

// ---------------------------------------------------------------------------
extern "C" void kernel_launch(void* const* d_in, const int* in_sizes, int n_in,
                              void* d_out, int out_size, void* d_ws,
                              size_t ws_size, hipStream_t stream) {
  const float* vis = (const float*)d_in[0];    // [32,1024,512]
  const int* ids = (const int*)d_in[1];        // [32,256,8]
  const float* emb = (const float*)d_in[2];    // [1024,512]
  const float* wq = (const float*)d_in[3];     // [512,512]
  const float* wk = (const float*)d_in[4];     // [512,512]
  const float* wvp = (const float*)d_in[5];    // [512,512]
  const float* wv2t = (const float*)d_in[6];   // [512,512]
  const float* dwk = (const float*)d_in[7];    // [512,1,3]
  const float* pwk = (const float*)d_in[8];    // [512,512,1]
  const float* lng = (const float*)d_in[9];    // [512]
  const float* lnb = (const float*)d_in[10];   // [512]
  const float* alpha = (const float*)d_in[11]; // scalar

  float* out_cls = (float*)d_out;              // [8192,1024]
  float* out_H = out_cls + (size_t)8192 * 1024;  // [8192,512]
  float* out_A = out_H + (size_t)8192 * 512;     // [8192,1024]

  // workspace layout (floats); total 218.1 MB
  float* wsf = (float*)d_ws;
  float* Kbuf = wsf;                       // 32768*512
  float* Vbuf = Kbuf + (size_t)32768 * 512;
  float* shmb = Vbuf + (size_t)32768 * 512;  // 8192*512
  float* mbuf = shmb + (size_t)8192 * 512;
  float* qbuf = mbuf + (size_t)8192 * 512;
  float* Qbuf = qbuf + (size_t)8192 * 512;
  float* Fvb = Qbuf + (size_t)8192 * 512;

  // 1) text front: gather + dwconv + silu + means
  text_front<<<8192, 256, 0, stream>>>(ids, emb, dwk, shmb, mbuf);
  // 2) m += shm @ pw^T   (pointwise conv folded through mean)
  gemm_abt<true><<<dim3(512 / 64, 8192 / 128), 256, 0, stream>>>(
      shmb, pwk, mbuf, 8192, 512, 512);
  // 3) LayerNorm -> q_txt
  ln_kernel<<<8192, 256, 0, stream>>>(mbuf, lng, lnb, qbuf);
  // 4) Q = q_txt @ wq^T
  gemm_abt<false><<<dim3(512 / 64, 8192 / 128), 256, 0, stream>>>(
      qbuf, wq, Qbuf, 8192, 512, 512);
  // 5) K = vis @ wk^T
  gemm_abt<false><<<dim3(512 / 64, 32768 / 128), 256, 0, stream>>>(
      vis, wk, Kbuf, 32768, 512, 512);
  // 6) V = vis @ wv^T
  gemm_abt<false><<<dim3(512 / 64, 32768 / 128), 256, 0, stream>>>(
      vis, wvp, Vbuf, 32768, 512, 512);
  // 7) banded attention -> A (full rows), Fv
  attn_kernel<<<8192, 256, 0, stream>>>(Qbuf, Kbuf, Vbuf, alpha, out_A, Fvb);
  // 8) H = Fv @ wv2t^T
  gemm_abt<false><<<dim3(512 / 64, 8192 / 128), 256, 0, stream>>>(
      Fvb, wv2t, out_H, 8192, 512, 512);
  // 9) cls = H @ emb^T
  gemm_abt<false><<<dim3(1024 / 64, 8192 / 128), 256, 0, stream>>>(
      out_H, emb, out_cls, 8192, 1024, 512);
}

// Round 2
// 301.271 us; speedup vs baseline: 3.2730x; 3.2730x over previous
//
#include <hip/hip_runtime.h>
#include <cmath>

typedef unsigned short u16;
typedef __attribute__((ext_vector_type(8))) short bf16x8;
typedef __attribute__((ext_vector_type(4))) float f32x4;
typedef __attribute__((ext_vector_type(8))) unsigned short u16x8;

#define B_  32
#define N_  1024
#define L_  256
#define S_  8
#define DT_ 512
#define BAND_ 16

__device__ __forceinline__ u16 f2bf(float f) {
  union { float f; unsigned u; } x; x.f = f;
  unsigned r = (x.u + 0x7fffu + ((x.u >> 16) & 1u)) >> 16;
  return (u16)r;
}
__device__ __forceinline__ float bf2f(u16 h) {
  union { unsigned u; float f; } x; x.u = ((unsigned)h) << 16;
  return x.f;
}

// ---------------------------------------------------------------------------
// f32 -> bf16 conversion (vectorized x4)
// ---------------------------------------------------------------------------
__global__ __launch_bounds__(256) void cvt_bf16(
    const float* __restrict__ in, u16* __restrict__ out, int n4) {
  int i = blockIdx.x * 256 + threadIdx.x;
  if (i < n4) {
    float4 v = ((const float4*)in)[i];
    ushort4 o;
    o.x = f2bf(v.x); o.y = f2bf(v.y); o.z = f2bf(v.z); o.w = f2bf(v.w);
    ((ushort4*)out)[i] = o;
  }
}

// ---------------------------------------------------------------------------
// K1: per (b,l): gather emb rows, depthwise conv (k=3, SAME, cross-corr),
// silu, mean over s -> shm (bf16); meanE -> mbuf (f32)
// ---------------------------------------------------------------------------
__global__ __launch_bounds__(256) void text_front(
    const int* __restrict__ ids, const float* __restrict__ emb,
    const float* __restrict__ dwk, u16* __restrict__ shm,
    float* __restrict__ mbuf) {
  int bl = blockIdx.x;
  int tid = threadIdx.x;
  __shared__ int sid[S_];
  if (tid < S_) sid[tid] = ids[bl * S_ + tid];
  __syncthreads();
  for (int c = tid; c < DT_; c += 256) {
    float x[S_];
#pragma unroll
    for (int s = 0; s < S_; ++s) x[s] = emb[(size_t)sid[s] * DT_ + c];
    float k0 = dwk[c * 3 + 0], k1 = dwk[c * 3 + 1], k2 = dwk[c * 3 + 2];
    float me = 0.f, sh = 0.f;
#pragma unroll
    for (int s = 0; s < S_; ++s) {
      float xm = (s > 0) ? x[s - 1] : 0.0f;
      float xp = (s < S_ - 1) ? x[s + 1] : 0.0f;
      float h = k0 * xm + k1 * x[s] + k2 * xp;
      float si = h / (1.0f + expf(-h));  // silu
      me += x[s];
      sh += si;
    }
    shm[(size_t)bl * DT_ + c] = f2bf(sh * (1.0f / S_));
    mbuf[(size_t)bl * DT_ + c] = me * (1.0f / S_);
  }
}

// ---------------------------------------------------------------------------
// bf16 MFMA GEMM (m97 structure): C[m][n] (+)= sum_k A[m][k]*B[n][k]
// A:[M,K] bf16 row-major, B:[N,K] bf16 row-major. Tile 128x128, BK=32,
// 256 threads (4 waves, 2x2 wave grid, each wave 64x64 = 4x4 16x16 frags).
// global_load_lds width=16, linear LDS [128][32].
// Requires M%128==0, N%128==0, K%32==0.
// ---------------------------------------------------------------------------
template <bool ACC, bool WF32, bool WBF16>
__global__ __launch_bounds__(256) void gemm_mfma(
    const u16* __restrict__ A, const u16* __restrict__ B,
    float* __restrict__ C, u16* __restrict__ Cb, int M, int N, int K) {
  __shared__ u16 As[4096];  // [128][32]
  __shared__ u16 Bs[4096];
  const int tid = threadIdx.x;
  const int w = tid >> 6;
  const int lane = tid & 63;
  const int bm = blockIdx.y << 7;
  const int bn = blockIdx.x << 7;
  const int wr = w >> 1, wc = w & 1;

  // staging: wave w, round i covers LDS bytes [i*4096 + w*1024 + lane*16)
  // -> row = i*64 + w*16 + lane/4, k-col = (lane&3)*8
  const int r0 = (w << 4) + (lane >> 2);
  const int kc = (lane & 3) << 3;
  const u16* Ag0 = A + (size_t)(bm + r0) * K + kc;
  const u16* Ag1 = Ag0 + (size_t)64 * K;
  const u16* Bg0 = B + (size_t)(bn + r0) * K + kc;
  const u16* Bg1 = Bg0 + (size_t)64 * K;
  u16* AsW0 = As + (w << 9);
  u16* AsW1 = As + 2048 + (w << 9);
  u16* BsW0 = Bs + (w << 9);
  u16* BsW1 = Bs + 2048 + (w << 9);

  // fragment ds_read offsets (u16 units): row*(32) + kgroup*8
  int aoff[4], boff[4];
#pragma unroll
  for (int m = 0; m < 4; ++m)
    aoff[m] = (((wr << 6) + (m << 4) + (lane & 15)) << 5) + ((lane >> 4) << 3);
#pragma unroll
  for (int n = 0; n < 4; ++n)
    boff[n] = (((wc << 6) + (n << 4) + (lane & 15)) << 5) + ((lane >> 4) << 3);

  f32x4 acc[4][4];
#pragma unroll
  for (int m = 0; m < 4; ++m)
#pragma unroll
    for (int n = 0; n < 4; ++n) acc[m][n] = (f32x4){0.f, 0.f, 0.f, 0.f};

  for (int kt = 0; kt < K; kt += 32) {
    __builtin_amdgcn_global_load_lds(
        (const __attribute__((address_space(1))) void*)(Ag0 + kt),
        (__attribute__((address_space(3))) void*)AsW0, 16, 0, 0);
    __builtin_amdgcn_global_load_lds(
        (const __attribute__((address_space(1))) void*)(Ag1 + kt),
        (__attribute__((address_space(3))) void*)AsW1, 16, 0, 0);
    __builtin_amdgcn_global_load_lds(
        (const __attribute__((address_space(1))) void*)(Bg0 + kt),
        (__attribute__((address_space(3))) void*)BsW0, 16, 0, 0);
    __builtin_amdgcn_global_load_lds(
        (const __attribute__((address_space(1))) void*)(Bg1 + kt),
        (__attribute__((address_space(3))) void*)BsW1, 16, 0, 0);
    __syncthreads();  // drains vmcnt before use
    bf16x8 af[4], bfr[4];
#pragma unroll
    for (int m = 0; m < 4; ++m) af[m] = *(const bf16x8*)(As + aoff[m]);
#pragma unroll
    for (int n = 0; n < 4; ++n) bfr[n] = *(const bf16x8*)(Bs + boff[n]);
#pragma unroll
    for (int m = 0; m < 4; ++m)
#pragma unroll
      for (int n = 0; n < 4; ++n)
        acc[m][n] = __builtin_amdgcn_mfma_f32_16x16x32_bf16(
            af[m], bfr[n], acc[m][n], 0, 0, 0);
    __syncthreads();  // before next staging overwrites LDS
  }

  // epilogue: C/D layout col=lane&15, row=(lane>>4)*4+j  [m89/m91]
  const int rb = bm + (wr << 6) + ((lane >> 4) << 2);
  const int cb = bn + (wc << 6) + (lane & 15);
#pragma unroll
  for (int m = 0; m < 4; ++m) {
#pragma unroll
    for (int n = 0; n < 4; ++n) {
      int col = cb + (n << 4);
#pragma unroll
      for (int j = 0; j < 4; ++j) {
        size_t idx = (size_t)(rb + (m << 4) + j) * N + col;
        float v = acc[m][n][j];
        if (ACC) v += C[idx];
        if (WF32) C[idx] = v;
        if (WBF16) Cb[idx] = f2bf(v);
      }
    }
  }
}

// ---------------------------------------------------------------------------
// LayerNorm over DT=512 per row; writes bf16 q_txt
// ---------------------------------------------------------------------------
__global__ __launch_bounds__(256) void ln_kernel(
    const float* __restrict__ m, const float* __restrict__ g,
    const float* __restrict__ bta, u16* __restrict__ q) {
  int row = blockIdx.x;
  int tid = threadIdx.x;
  float v0 = m[(size_t)row * 512 + tid];
  float v1 = m[(size_t)row * 512 + 256 + tid];
  __shared__ float red[4], red2[4];
  float s = v0 + v1;
#pragma unroll
  for (int d = 32; d; d >>= 1) s += __shfl_xor(s, d);
  if ((tid & 63) == 0) red[tid >> 6] = s;
  __syncthreads();
  float mu = (red[0] + red[1] + red[2] + red[3]) * (1.0f / 512.0f);
  float d0 = v0 - mu, d1 = v1 - mu;
  float s2 = d0 * d0 + d1 * d1;
#pragma unroll
  for (int d = 32; d; d >>= 1) s2 += __shfl_xor(s2, d);
  if ((tid & 63) == 0) red2[tid >> 6] = s2;
  __syncthreads();
  float var = (red2[0] + red2[1] + red2[2] + red2[3]) * (1.0f / 512.0f);
  float r = rsqrtf(var + 1e-5f);
  q[(size_t)row * 512 + tid] = f2bf(d0 * r * g[tid] + bta[tid]);
  q[(size_t)row * 512 + 256 + tid] = f2bf(d1 * r * g[tid + 256] + bta[tid + 256]);
}

// ---------------------------------------------------------------------------
// banded attention. One block per (b,l). center = floor(1023*l/255).
// KV: [32768][1024] bf16, cols 0..511 = K, 512..1023 = V.
// ---------------------------------------------------------------------------
__global__ __launch_bounds__(256) void attn_kernel(
    const float* __restrict__ Q, const u16* __restrict__ KV,
    const float* __restrict__ alpha_p, float* __restrict__ A,
    u16* __restrict__ Fv) {
  int bl = blockIdx.x;
  int b = bl >> 8, l = bl & 255;
  int tid = threadIdx.x;
  int c = (1023 * l) / 255;
  int lo = max(0, c - BAND_), hi = min(N_ - 1, c + BAND_);
  int W = hi - lo + 1;  // <= 33
  __shared__ float logit[33];
  __shared__ float av[33];
  int wv = tid >> 6, lane = tid & 63;
  // Q slice in registers (each lane owns 8 channels)
  float qr[8];
  {
    float4 q1 = *(const float4*)(Q + (size_t)bl * 512 + lane * 8);
    float4 q2 = *(const float4*)(Q + (size_t)bl * 512 + lane * 8 + 4);
    qr[0] = q1.x; qr[1] = q1.y; qr[2] = q1.z; qr[3] = q1.w;
    qr[4] = q2.x; qr[5] = q2.y; qr[6] = q2.z; qr[7] = q2.w;
  }
  for (int j = wv; j < W; j += 4) {
    const u16x8 kv =
        *(const u16x8*)(KV + ((size_t)(b * N_ + lo + j)) * 1024 + lane * 8);
    float s = 0.f;
#pragma unroll
    for (int t = 0; t < 8; ++t) s += bf2f(kv[t]) * qr[t];
#pragma unroll
    for (int d = 32; d; d >>= 1) s += __shfl_down(s, d);
    if (lane == 0) logit[j] = s;
  }
  __syncthreads();
  if (tid < 64) {
    float al = *alpha_p;
    float x = -INFINITY;
    if (tid < W) {
      float dirv = al * ((float)(c - (lo + tid)) / 16.000001f);
      x = logit[tid] * 0.044194173824159216f + dirv;  // * 512^-0.5
    }
    float mx = x;
#pragma unroll
    for (int d = 32; d; d >>= 1) mx = fmaxf(mx, __shfl_xor(mx, d));
    float e = (tid < W) ? expf(x - mx) : 0.0f;
    float sm = e;
#pragma unroll
    for (int d = 32; d; d >>= 1) sm += __shfl_xor(sm, d);
    if (tid < W) av[tid] = e / sm;
  }
  __syncthreads();
  float* Arow = A + (size_t)bl * N_;
  for (int p = tid; p < N_; p += 256)
    Arow[p] = (p >= lo && p <= hi) ? av[p - lo] : 0.0f;
  u16* fr = Fv + (size_t)bl * 512;
  for (int ch = tid; ch < 512; ch += 256) {
    float acc = 0.f;
    for (int j = 0; j < W; ++j)
      acc += av[j] * bf2f(KV[((size_t)(b * N_ + lo + j)) * 1024 + 512 + ch]);
    fr[ch] = f2bf(acc);
  }
}

// ---------------------------------------------------------------------------
extern "C" void kernel_launch(void* const* d_in, const int* in_sizes, int n_in,
                              void* d_out, int out_size, void* d_ws,
                              size_t ws_size, hipStream_t stream) {
  const float* vis = (const float*)d_in[0];    // [32,1024,512]
  const int* ids = (const int*)d_in[1];        // [32,256,8]
  const float* emb = (const float*)d_in[2];    // [1024,512]
  const float* wq = (const float*)d_in[3];     // [512,512]
  const float* wk = (const float*)d_in[4];     // [512,512]
  const float* wvp = (const float*)d_in[5];    // [512,512]
  const float* wv2t = (const float*)d_in[6];   // [512,512]
  const float* dwk = (const float*)d_in[7];    // [512,1,3]
  const float* pwk = (const float*)d_in[8];    // [512,512,1]
  const float* lng = (const float*)d_in[9];    // [512]
  const float* lnb = (const float*)d_in[10];   // [512]
  const float* alpha = (const float*)d_in[11]; // scalar

  float* out_cls = (float*)d_out;                // [8192,1024]
  float* out_H = out_cls + (size_t)8192 * 1024;  // [8192,512]
  float* out_A = out_H + (size_t)8192 * 512;     // [8192,1024]

  // workspace layout  (~171 MB)
  char* p = (char*)d_ws;
  u16* visb = (u16*)p;              p += (size_t)32768 * 512 * 2;
  u16* KVb  = (u16*)p;              p += (size_t)32768 * 1024 * 2;
  u16* embb = (u16*)p;              p += (size_t)1024 * 512 * 2;
  u16* wqb  = (u16*)p;              p += (size_t)512 * 512 * 2;
  u16* wkvb = (u16*)p;              p += (size_t)1024 * 512 * 2;
  u16* wv2tb= (u16*)p;              p += (size_t)512 * 512 * 2;
  u16* pwkb = (u16*)p;              p += (size_t)512 * 512 * 2;
  u16* shmb = (u16*)p;              p += (size_t)8192 * 512 * 2;
  float* mbuf = (float*)p;          p += (size_t)8192 * 512 * 4;
  u16* qbuf = (u16*)p;              p += (size_t)8192 * 512 * 2;
  float* Qbuf = (float*)p;          p += (size_t)8192 * 512 * 4;
  u16* Fvb  = (u16*)p;              p += (size_t)8192 * 512 * 2;
  u16* Hb   = (u16*)p;              p += (size_t)8192 * 512 * 2;

  // conversions to bf16
  cvt_bf16<<<16384, 256, 0, stream>>>(vis, visb, 32768 * 512 / 4);
  cvt_bf16<<<512, 256, 0, stream>>>(emb, embb, 1024 * 512 / 4);
  cvt_bf16<<<256, 256, 0, stream>>>(wq, wqb, 512 * 512 / 4);
  cvt_bf16<<<256, 256, 0, stream>>>(wk, wkvb, 512 * 512 / 4);
  cvt_bf16<<<256, 256, 0, stream>>>(wvp, wkvb + (size_t)512 * 512, 512 * 512 / 4);
  cvt_bf16<<<256, 256, 0, stream>>>(wv2t, wv2tb, 512 * 512 / 4);
  cvt_bf16<<<256, 256, 0, stream>>>(pwk, pwkb, 512 * 512 / 4);

  // KV = vis @ [wk;wv]^T  -> bf16 [32768][1024]
  gemm_mfma<false, false, true><<<dim3(8, 256), 256, 0, stream>>>(
      visb, wkvb, nullptr, KVb, 32768, 1024, 512);

  // text front: gather + dwconv + silu + means
  text_front<<<8192, 256, 0, stream>>>(ids, emb, dwk, shmb, mbuf);
  // m += shm_mean @ pw^T  (pointwise conv folded through mean)
  gemm_mfma<true, true, false><<<dim3(4, 64), 256, 0, stream>>>(
      shmb, pwkb, mbuf, nullptr, 8192, 512, 512);
  // LayerNorm -> q_txt (bf16)
  ln_kernel<<<8192, 256, 0, stream>>>(mbuf, lng, lnb, qbuf);
  // Q = q_txt @ wq^T (f32 out)
  gemm_mfma<false, true, false><<<dim3(4, 64), 256, 0, stream>>>(
      qbuf, wqb, Qbuf, nullptr, 8192, 512, 512);
  // banded attention -> A (full rows, f32), Fv (bf16)
  attn_kernel<<<8192, 256, 0, stream>>>(Qbuf, KVb, alpha, out_A, Fvb);
  // H = Fv @ wv2t^T (f32 out + bf16 copy)
  gemm_mfma<false, true, true><<<dim3(4, 64), 256, 0, stream>>>(
      Fvb, wv2tb, out_H, Hb, 8192, 512, 512);
  // cls = H @ emb^T (f32 out)
  gemm_mfma<false, true, false><<<dim3(8, 64), 256, 0, stream>>>(
      Hb, embb, out_cls, nullptr, 8192, 1024, 512);
}

// Round 3
// 285.669 us; speedup vs baseline: 3.4517x; 1.0546x over previous
//
#include <hip/hip_runtime.h>
#include <cmath>

typedef unsigned short u16;
typedef __attribute__((ext_vector_type(8))) short bf16x8;
typedef __attribute__((ext_vector_type(4))) float f32x4;
typedef __attribute__((ext_vector_type(8))) unsigned short u16x8;

#define B_  32
#define N_  1024
#define L_  256
#define S_  8
#define DT_ 512
#define BAND_ 16

__device__ __forceinline__ u16 f2bf(float f) {
  union { float f; unsigned u; } x; x.f = f;
  unsigned r = (x.u + 0x7fffu + ((x.u >> 16) & 1u)) >> 16;
  return (u16)r;
}
__device__ __forceinline__ float bf2f(u16 h) {
  union { unsigned u; float f; } x; x.u = ((unsigned)h) << 16;
  return x.f;
}

// ---------------------------------------------------------------------------
// f32 -> bf16 conversion (vectorized x4)
// ---------------------------------------------------------------------------
__global__ __launch_bounds__(256) void cvt_bf16(
    const float* __restrict__ in, u16* __restrict__ out, int n4) {
  int i = blockIdx.x * 256 + threadIdx.x;
  if (i < n4) {
    float4 v = ((const float4*)in)[i];
    ushort4 o;
    o.x = f2bf(v.x); o.y = f2bf(v.y); o.z = f2bf(v.z); o.w = f2bf(v.w);
    ((ushort4*)out)[i] = o;
  }
}

// ---------------------------------------------------------------------------
// K1: per (b,l): gather emb rows, depthwise conv (k=3, SAME, cross-corr),
// silu, mean over s -> shm (bf16); meanE -> mbuf (f32)
// ---------------------------------------------------------------------------
__global__ __launch_bounds__(256) void text_front(
    const int* __restrict__ ids, const float* __restrict__ emb,
    const float* __restrict__ dwk, u16* __restrict__ shm,
    float* __restrict__ mbuf) {
  int bl = blockIdx.x;
  int tid = threadIdx.x;
  __shared__ int sid[S_];
  if (tid < S_) sid[tid] = ids[bl * S_ + tid];
  __syncthreads();
  for (int c = tid; c < DT_; c += 256) {
    float x[S_];
#pragma unroll
    for (int s = 0; s < S_; ++s) x[s] = emb[(size_t)sid[s] * DT_ + c];
    float k0 = dwk[c * 3 + 0], k1 = dwk[c * 3 + 1], k2 = dwk[c * 3 + 2];
    float me = 0.f, sh = 0.f;
#pragma unroll
    for (int s = 0; s < S_; ++s) {
      float xm = (s > 0) ? x[s - 1] : 0.0f;
      float xp = (s < S_ - 1) ? x[s + 1] : 0.0f;
      float h = k0 * xm + k1 * x[s] + k2 * xp;
      float si = h / (1.0f + expf(-h));  // silu
      me += x[s];
      sh += si;
    }
    shm[(size_t)bl * DT_ + c] = f2bf(sh * (1.0f / S_));
    mbuf[(size_t)bl * DT_ + c] = me * (1.0f / S_);
  }
}

// ---------------------------------------------------------------------------
// bf16 MFMA GEMM (m97 structure): C[m][n] (+)= sum_k A[m][k]*B[n][k]
// ---------------------------------------------------------------------------
template <bool ACC, bool WF32, bool WBF16>
__global__ __launch_bounds__(256) void gemm_mfma(
    const u16* __restrict__ A, const u16* __restrict__ B,
    float* __restrict__ C, u16* __restrict__ Cb, int M, int N, int K) {
  __shared__ u16 As[4096];  // [128][32]
  __shared__ u16 Bs[4096];
  const int tid = threadIdx.x;
  const int w = tid >> 6;
  const int lane = tid & 63;
  const int bm = blockIdx.y << 7;
  const int bn = blockIdx.x << 7;
  const int wr = w >> 1, wc = w & 1;

  const int r0 = (w << 4) + (lane >> 2);
  const int kc = (lane & 3) << 3;
  const u16* Ag0 = A + (size_t)(bm + r0) * K + kc;
  const u16* Ag1 = Ag0 + (size_t)64 * K;
  const u16* Bg0 = B + (size_t)(bn + r0) * K + kc;
  const u16* Bg1 = Bg0 + (size_t)64 * K;
  u16* AsW0 = As + (w << 9);
  u16* AsW1 = As + 2048 + (w << 9);
  u16* BsW0 = Bs + (w << 9);
  u16* BsW1 = Bs + 2048 + (w << 9);

  int aoff[4], boff[4];
#pragma unroll
  for (int m = 0; m < 4; ++m)
    aoff[m] = (((wr << 6) + (m << 4) + (lane & 15)) << 5) + ((lane >> 4) << 3);
#pragma unroll
  for (int n = 0; n < 4; ++n)
    boff[n] = (((wc << 6) + (n << 4) + (lane & 15)) << 5) + ((lane >> 4) << 3);

  f32x4 acc[4][4];
#pragma unroll
  for (int m = 0; m < 4; ++m)
#pragma unroll
    for (int n = 0; n < 4; ++n) acc[m][n] = (f32x4){0.f, 0.f, 0.f, 0.f};

  for (int kt = 0; kt < K; kt += 32) {
    __builtin_amdgcn_global_load_lds(
        (const __attribute__((address_space(1))) void*)(Ag0 + kt),
        (__attribute__((address_space(3))) void*)AsW0, 16, 0, 0);
    __builtin_amdgcn_global_load_lds(
        (const __attribute__((address_space(1))) void*)(Ag1 + kt),
        (__attribute__((address_space(3))) void*)AsW1, 16, 0, 0);
    __builtin_amdgcn_global_load_lds(
        (const __attribute__((address_space(1))) void*)(Bg0 + kt),
        (__attribute__((address_space(3))) void*)BsW0, 16, 0, 0);
    __builtin_amdgcn_global_load_lds(
        (const __attribute__((address_space(1))) void*)(Bg1 + kt),
        (__attribute__((address_space(3))) void*)BsW1, 16, 0, 0);
    __syncthreads();
    bf16x8 af[4], bfr[4];
#pragma unroll
    for (int m = 0; m < 4; ++m) af[m] = *(const bf16x8*)(As + aoff[m]);
#pragma unroll
    for (int n = 0; n < 4; ++n) bfr[n] = *(const bf16x8*)(Bs + boff[n]);
#pragma unroll
    for (int m = 0; m < 4; ++m)
#pragma unroll
      for (int n = 0; n < 4; ++n)
        acc[m][n] = __builtin_amdgcn_mfma_f32_16x16x32_bf16(
            af[m], bfr[n], acc[m][n], 0, 0, 0);
    __syncthreads();
  }

  const int rb = bm + (wr << 6) + ((lane >> 4) << 2);
  const int cb = bn + (wc << 6) + (lane & 15);
#pragma unroll
  for (int m = 0; m < 4; ++m) {
#pragma unroll
    for (int n = 0; n < 4; ++n) {
      int col = cb + (n << 4);
#pragma unroll
      for (int j = 0; j < 4; ++j) {
        size_t idx = (size_t)(rb + (m << 4) + j) * N + col;
        float v = acc[m][n][j];
        if (ACC) v += C[idx];
        if (WF32) C[idx] = v;
        if (WBF16) Cb[idx] = f2bf(v);
      }
    }
  }
}

// ---------------------------------------------------------------------------
// LayerNorm over DT=512 per row; writes bf16 q_txt
// ---------------------------------------------------------------------------
__global__ __launch_bounds__(256) void ln_kernel(
    const float* __restrict__ m, const float* __restrict__ g,
    const float* __restrict__ bta, u16* __restrict__ q) {
  int row = blockIdx.x;
  int tid = threadIdx.x;
  float v0 = m[(size_t)row * 512 + tid];
  float v1 = m[(size_t)row * 512 + 256 + tid];
  __shared__ float red[4], red2[4];
  float s = v0 + v1;
#pragma unroll
  for (int d = 32; d; d >>= 1) s += __shfl_xor(s, d);
  if ((tid & 63) == 0) red[tid >> 6] = s;
  __syncthreads();
  float mu = (red[0] + red[1] + red[2] + red[3]) * (1.0f / 512.0f);
  float d0 = v0 - mu, d1 = v1 - mu;
  float s2 = d0 * d0 + d1 * d1;
#pragma unroll
  for (int d = 32; d; d >>= 1) s2 += __shfl_xor(s2, d);
  if ((tid & 63) == 0) red2[tid >> 6] = s2;
  __syncthreads();
  float var = (red2[0] + red2[1] + red2[2] + red2[3]) * (1.0f / 512.0f);
  float r = rsqrtf(var + 1e-5f);
  q[(size_t)row * 512 + tid] = f2bf(d0 * r * g[tid] + bta[tid]);
  q[(size_t)row * 512 + 256 + tid] = f2bf(d1 * r * g[tid + 256] + bta[tid + 256]);
}

// ---------------------------------------------------------------------------
// Banded attention, l-grouped for KV reuse.
// Block = (b, lgroup of 8 l). 4 waves x 2 l each. Q in registers,
// logit j lives in lane j (register softmax, no block barriers).
// KV: [32768][1024] bf16, cols 0..511 = K, 512..1023 = V.
// ---------------------------------------------------------------------------
__global__ __launch_bounds__(256) void attn_kernel(
    const float* __restrict__ Q, const u16* __restrict__ KV,
    const float* __restrict__ alpha_p, float* __restrict__ A,
    u16* __restrict__ Fv) {
  __shared__ float av_s[8][64];
  const int blk = blockIdx.x;
  const int b = blk >> 5, lg = blk & 31;
  const int tid = threadIdx.x;
  const int w = tid >> 6, lane = tid & 63;
  const float al = *alpha_p;

#pragma unroll
  for (int i = 0; i < 2; ++i) {
    const int wl = w * 2 + i;
    const int l = lg * 8 + wl;
    const int c = (1023 * l) / 255;
    const int lo = max(0, c - BAND_), hi = min(N_ - 1, c + BAND_);
    const int W = hi - lo + 1;  // 17..33
    // Q slice into registers (lane owns 8 channels)
    float qr[8];
    {
      const float4 q1 = *(const float4*)(Q + (size_t)(b * L_ + l) * 512 + lane * 8);
      const float4 q2 = *(const float4*)(Q + (size_t)(b * L_ + l) * 512 + lane * 8 + 4);
      qr[0] = q1.x; qr[1] = q1.y; qr[2] = q1.z; qr[3] = q1.w;
      qr[4] = q2.x; qr[5] = q2.y; qr[6] = q2.z; qr[7] = q2.w;
    }
    // QK^T: lane j ends up holding logit j
    float mylogit = 0.f;
    for (int j = 0; j < W; ++j) {
      const u16x8 kv =
          *(const u16x8*)(KV + ((size_t)(b * N_ + lo + j)) * 1024 + lane * 8);
      float s = 0.f;
#pragma unroll
      for (int t = 0; t < 8; ++t) s += bf2f(kv[t]) * qr[t];
#pragma unroll
      for (int d = 32; d; d >>= 1) s += __shfl_xor(s, d);
      mylogit = (lane == j) ? s : mylogit;
    }
    // register softmax across lanes 0..W-1
    float x = (lane < W)
                  ? mylogit * 0.044194173824159216f +
                        al * ((float)(c - (lo + lane)) * (1.0f / 16.000001f))
                  : -INFINITY;
    float mx = x;
#pragma unroll
    for (int d = 32; d; d >>= 1) mx = fmaxf(mx, __shfl_xor(mx, d));
    float e = (lane < W) ? expf(x - mx) : 0.0f;
    float sm = e;
#pragma unroll
    for (int d = 32; d; d >>= 1) sm += __shfl_xor(sm, d);
    av_s[wl][lane] = (lane < W) ? (e / sm) : 0.0f;
    // A row (float4, zeros outside band)
    float* Arow = A + (size_t)(b * L_ + l) * N_;
    for (int p4 = lane; p4 < N_ / 4; p4 += 64) {
      int p = p4 * 4;
      float4 v;
      v.x = (p + 0 >= lo && p + 0 <= hi) ? av_s[wl][p + 0 - lo] : 0.0f;
      v.y = (p + 1 >= lo && p + 1 <= hi) ? av_s[wl][p + 1 - lo] : 0.0f;
      v.z = (p + 2 >= lo && p + 2 <= hi) ? av_s[wl][p + 2 - lo] : 0.0f;
      v.w = (p + 3 >= lo && p + 3 <= hi) ? av_s[wl][p + 3 - lo] : 0.0f;
      ((float4*)Arow)[p4] = v;
    }
    // PV: acc over band rows, lane owns 8 V channels
    float acc[8] = {};
    for (int j = 0; j < W; ++j) {
      const float avj = av_s[wl][j];
      const u16x8 v =
          *(const u16x8*)(KV + ((size_t)(b * N_ + lo + j)) * 1024 + 512 + lane * 8);
#pragma unroll
      for (int t = 0; t < 8; ++t) acc[t] += avj * bf2f(v[t]);
    }
    u16x8 fo;
#pragma unroll
    for (int t = 0; t < 8; ++t) fo[t] = f2bf(acc[t]);
    *(u16x8*)(Fv + (size_t)(b * L_ + l) * 512 + lane * 8) = fo;
  }
}

// ---------------------------------------------------------------------------
extern "C" void kernel_launch(void* const* d_in, const int* in_sizes, int n_in,
                              void* d_out, int out_size, void* d_ws,
                              size_t ws_size, hipStream_t stream) {
  const float* vis = (const float*)d_in[0];    // [32,1024,512]
  const int* ids = (const int*)d_in[1];        // [32,256,8]
  const float* emb = (const float*)d_in[2];    // [1024,512]
  const float* wq = (const float*)d_in[3];     // [512,512]
  const float* wk = (const float*)d_in[4];     // [512,512]
  const float* wvp = (const float*)d_in[5];    // [512,512]
  const float* wv2t = (const float*)d_in[6];   // [512,512]
  const float* dwk = (const float*)d_in[7];    // [512,1,3]
  const float* pwk = (const float*)d_in[8];    // [512,512,1]
  const float* lng = (const float*)d_in[9];    // [512]
  const float* lnb = (const float*)d_in[10];   // [512]
  const float* alpha = (const float*)d_in[11]; // scalar

  float* out_cls = (float*)d_out;                // [8192,1024]
  float* out_H = out_cls + (size_t)8192 * 1024;  // [8192,512]
  float* out_A = out_H + (size_t)8192 * 512;     // [8192,1024]

  // workspace layout  (~171 MB)
  char* p = (char*)d_ws;
  u16* visb = (u16*)p;              p += (size_t)32768 * 512 * 2;
  u16* KVb  = (u16*)p;              p += (size_t)32768 * 1024 * 2;
  u16* embb = (u16*)p;              p += (size_t)1024 * 512 * 2;
  u16* wqb  = (u16*)p;              p += (size_t)512 * 512 * 2;
  u16* wkvb = (u16*)p;              p += (size_t)1024 * 512 * 2;
  u16* wv2tb= (u16*)p;              p += (size_t)512 * 512 * 2;
  u16* pwkb = (u16*)p;              p += (size_t)512 * 512 * 2;
  u16* shmb = (u16*)p;              p += (size_t)8192 * 512 * 2;
  float* mbuf = (float*)p;          p += (size_t)8192 * 512 * 4;
  u16* qbuf = (u16*)p;              p += (size_t)8192 * 512 * 2;
  float* Qbuf = (float*)p;          p += (size_t)8192 * 512 * 4;
  u16* Fvb  = (u16*)p;              p += (size_t)8192 * 512 * 2;
  u16* Hb   = (u16*)p;              p += (size_t)8192 * 512 * 2;

  // conversions to bf16
  cvt_bf16<<<16384, 256, 0, stream>>>(vis, visb, 32768 * 512 / 4);
  cvt_bf16<<<512, 256, 0, stream>>>(emb, embb, 1024 * 512 / 4);
  cvt_bf16<<<256, 256, 0, stream>>>(wq, wqb, 512 * 512 / 4);
  cvt_bf16<<<256, 256, 0, stream>>>(wk, wkvb, 512 * 512 / 4);
  cvt_bf16<<<256, 256, 0, stream>>>(wvp, wkvb + (size_t)512 * 512, 512 * 512 / 4);
  cvt_bf16<<<256, 256, 0, stream>>>(wv2t, wv2tb, 512 * 512 / 4);
  cvt_bf16<<<256, 256, 0, stream>>>(pwk, pwkb, 512 * 512 / 4);

  // KV = vis @ [wk;wv]^T  -> bf16 [32768][1024]
  gemm_mfma<false, false, true><<<dim3(8, 256), 256, 0, stream>>>(
      visb, wkvb, nullptr, KVb, 32768, 1024, 512);

  // text front: gather + dwconv + silu + means
  text_front<<<8192, 256, 0, stream>>>(ids, emb, dwk, shmb, mbuf);
  // m += shm_mean @ pw^T  (pointwise conv folded through mean)
  gemm_mfma<true, true, false><<<dim3(4, 64), 256, 0, stream>>>(
      shmb, pwkb, mbuf, nullptr, 8192, 512, 512);
  // LayerNorm -> q_txt (bf16)
  ln_kernel<<<8192, 256, 0, stream>>>(mbuf, lng, lnb, qbuf);
  // Q = q_txt @ wq^T (f32 out)
  gemm_mfma<false, true, false><<<dim3(4, 64), 256, 0, stream>>>(
      qbuf, wqb, Qbuf, nullptr, 8192, 512, 512);
  // banded attention -> A (full rows, f32), Fv (bf16)
  attn_kernel<<<1024, 256, 0, stream>>>(Qbuf, KVb, alpha, out_A, Fvb);
  // H = Fv @ wv2t^T (f32 out + bf16 copy)
  gemm_mfma<false, true, true><<<dim3(4, 64), 256, 0, stream>>>(
      Fvb, wv2tb, out_H, Hb, 8192, 512, 512);
  // cls = H @ emb^T (f32 out)
  gemm_mfma<false, true, false><<<dim3(8, 64), 256, 0, stream>>>(
      Hb, embb, out_cls, nullptr, 8192, 1024, 512);
}

// Round 4
// 250.538 us; speedup vs baseline: 3.9357x; 1.1402x over previous
//
#include <hip/hip_runtime.h>
#include <cmath>

typedef unsigned short u16;
typedef __attribute__((ext_vector_type(8))) short bf16x8;
typedef __attribute__((ext_vector_type(4))) float f32x4;
typedef __attribute__((ext_vector_type(8))) unsigned short u16x8;

#define B_  32
#define N_  1024
#define L_  256
#define S_  8
#define DT_ 512
#define BAND_ 16

__device__ __forceinline__ u16 f2bf(float f) {
  union { float f; unsigned u; } x; x.f = f;
  unsigned r = (x.u + 0x7fffu + ((x.u >> 16) & 1u)) >> 16;
  return (u16)r;
}
__device__ __forceinline__ float bf2f(u16 h) {
  union { unsigned u; float f; } x; x.u = ((unsigned)h) << 16;
  return x.f;
}

// ---------------------------------------------------------------------------
// f32 -> bf16 conversion (vectorized x4)
// ---------------------------------------------------------------------------
__global__ __launch_bounds__(256) void cvt_bf16(
    const float* __restrict__ in, u16* __restrict__ out, int n4) {
  int i = blockIdx.x * 256 + threadIdx.x;
  if (i < n4) {
    float4 v = ((const float4*)in)[i];
    ushort4 o;
    o.x = f2bf(v.x); o.y = f2bf(v.y); o.z = f2bf(v.z); o.w = f2bf(v.w);
    ((ushort4*)out)[i] = o;
  }
}

// ---------------------------------------------------------------------------
// All small weights in one launch. float4 counts:
// emb 131072 | wq 65536 | wk 65536 | wv 65536 | wv2t 65536 | pwk 65536
// (each segment a multiple of 256 -> branch is block-uniform)
// ---------------------------------------------------------------------------
__global__ __launch_bounds__(256) void cvt_weights(
    const float* __restrict__ e, const float* __restrict__ q,
    const float* __restrict__ k, const float* __restrict__ v,
    const float* __restrict__ t, const float* __restrict__ pw,
    u16* __restrict__ eo, u16* __restrict__ qo, u16* __restrict__ kvo,
    u16* __restrict__ to, u16* __restrict__ po) {
  int i = blockIdx.x * 256 + threadIdx.x;
  const float* src; u16* dst; int soff, doff;
  if (i < 131072)      { src = e;  dst = eo;  soff = i;          doff = soff; }
  else if (i < 196608) { src = q;  dst = qo;  soff = i - 131072; doff = soff; }
  else if (i < 262144) { src = k;  dst = kvo; soff = i - 196608; doff = soff; }
  else if (i < 327680) { src = v;  dst = kvo; soff = i - 262144; doff = soff + 65536; }
  else if (i < 393216) { src = t;  dst = to;  soff = i - 327680; doff = soff; }
  else                 { src = pw; dst = po;  soff = i - 393216; doff = soff; }
  float4 vv = ((const float4*)src)[soff];
  ushort4 o;
  o.x = f2bf(vv.x); o.y = f2bf(vv.y); o.z = f2bf(vv.z); o.w = f2bf(vv.w);
  ((ushort4*)dst)[doff] = o;
}

// ---------------------------------------------------------------------------
// K1: per (b,l): gather emb rows, depthwise conv (k=3, SAME, cross-corr),
// silu, mean over s -> shm (bf16); meanE -> mbuf (f32)
// ---------------------------------------------------------------------------
__global__ __launch_bounds__(256) void text_front(
    const int* __restrict__ ids, const float* __restrict__ emb,
    const float* __restrict__ dwk, u16* __restrict__ shm,
    float* __restrict__ mbuf) {
  int bl = blockIdx.x;
  int tid = threadIdx.x;
  __shared__ int sid[S_];
  if (tid < S_) sid[tid] = ids[bl * S_ + tid];
  __syncthreads();
  for (int c = tid; c < DT_; c += 256) {
    float x[S_];
#pragma unroll
    for (int s = 0; s < S_; ++s) x[s] = emb[(size_t)sid[s] * DT_ + c];
    float k0 = dwk[c * 3 + 0], k1 = dwk[c * 3 + 1], k2 = dwk[c * 3 + 2];
    float me = 0.f, sh = 0.f;
#pragma unroll
    for (int s = 0; s < S_; ++s) {
      float xm = (s > 0) ? x[s - 1] : 0.0f;
      float xp = (s < S_ - 1) ? x[s + 1] : 0.0f;
      float h = k0 * xm + k1 * x[s] + k2 * xp;
      float si = h / (1.0f + expf(-h));  // silu
      me += x[s];
      sh += si;
    }
    shm[(size_t)bl * DT_ + c] = f2bf(sh * (1.0f / S_));
    mbuf[(size_t)bl * DT_ + c] = me * (1.0f / S_);
  }
}

// ---------------------------------------------------------------------------
// bf16 MFMA GEMM, 2-phase double-buffered (T3-min) + XCD-chunked swizzle (T1).
// C[m][n] (+)= sum_k A[m][k]*B[n][k]; A:[M,K], B:[N,K] bf16 row-major.
// Tile 128x128, BK=32, 256 threads (2x2 waves, 4x4 16x16 frags each).
// LDS: 2 x (As 8KB + Bs 8KB) = 32 KB.
// ---------------------------------------------------------------------------
template <bool ACC, bool WF32, bool WBF16>
__global__ __launch_bounds__(256) void gemm_mfma(
    const u16* __restrict__ A, const u16* __restrict__ B,
    float* __restrict__ C, u16* __restrict__ Cb, int M, int N, int K) {
  __shared__ u16 As[8192];  // [2][128][32]
  __shared__ u16 Bs[8192];
  const int tid = threadIdx.x;
  const int w = tid >> 6;
  const int lane = tid & 63;

  // XCD-chunked bijective swizzle (nwg % 8 == 0 for all our launches)
  const int gx = gridDim.x;
  const int bid = blockIdx.y * gx + blockIdx.x;
  const int nwg = gx * gridDim.y;
  const int logical = (bid & 7) * (nwg >> 3) + (bid >> 3);
  const int bm = (logical / gx) << 7;
  const int bn = (logical % gx) << 7;
  const int wr = w >> 1, wc = w & 1;

  const int r0 = (w << 4) + (lane >> 2);
  const int kc = (lane & 3) << 3;
  const u16* Ag0 = A + (size_t)(bm + r0) * K + kc;
  const u16* Ag1 = Ag0 + (size_t)64 * K;
  const u16* Bg0 = B + (size_t)(bn + r0) * K + kc;
  const u16* Bg1 = Bg0 + (size_t)64 * K;

  int aoff[4], boff[4];
#pragma unroll
  for (int m = 0; m < 4; ++m)
    aoff[m] = (((wr << 6) + (m << 4) + (lane & 15)) << 5) + ((lane >> 4) << 3);
#pragma unroll
  for (int n = 0; n < 4; ++n)
    boff[n] = (((wc << 6) + (n << 4) + (lane & 15)) << 5) + ((lane >> 4) << 3);

  f32x4 acc[4][4];
#pragma unroll
  for (int m = 0; m < 4; ++m)
#pragma unroll
    for (int n = 0; n < 4; ++n) acc[m][n] = (f32x4){0.f, 0.f, 0.f, 0.f};

#define STAGE(buf, kt)                                                        \
  {                                                                           \
    u16* as_ = As + (buf) * 4096 + (w << 9);                                  \
    u16* bs_ = Bs + (buf) * 4096 + (w << 9);                                  \
    __builtin_amdgcn_global_load_lds(                                         \
        (const __attribute__((address_space(1))) void*)(Ag0 + (kt)),          \
        (__attribute__((address_space(3))) void*)as_, 16, 0, 0);              \
    __builtin_amdgcn_global_load_lds(                                         \
        (const __attribute__((address_space(1))) void*)(Ag1 + (kt)),          \
        (__attribute__((address_space(3))) void*)(as_ + 2048), 16, 0, 0);     \
    __builtin_amdgcn_global_load_lds(                                         \
        (const __attribute__((address_space(1))) void*)(Bg0 + (kt)),          \
        (__attribute__((address_space(3))) void*)bs_, 16, 0, 0);              \
    __builtin_amdgcn_global_load_lds(                                         \
        (const __attribute__((address_space(1))) void*)(Bg1 + (kt)),          \
        (__attribute__((address_space(3))) void*)(bs_ + 2048), 16, 0, 0);     \
  }

  const int nt = K >> 5;
  STAGE(0, 0);
  __syncthreads();  // tile 0 staged (vmcnt(0) drained by syncthreads)
  int cur = 0;
  for (int t = 0; t < nt; ++t) {
    if (t + 1 < nt) STAGE(cur ^ 1, (t + 1) << 5);  // prefetch overlaps compute
    const u16* Ab = As + cur * 4096;
    const u16* Bb = Bs + cur * 4096;
    bf16x8 af[4], bfr[4];
#pragma unroll
    for (int m = 0; m < 4; ++m) af[m] = *(const bf16x8*)(Ab + aoff[m]);
#pragma unroll
    for (int n = 0; n < 4; ++n) bfr[n] = *(const bf16x8*)(Bb + boff[n]);
#pragma unroll
    for (int m = 0; m < 4; ++m)
#pragma unroll
      for (int n = 0; n < 4; ++n)
        acc[m][n] = __builtin_amdgcn_mfma_f32_16x16x32_bf16(
            af[m], bfr[n], acc[m][n], 0, 0, 0);
    __syncthreads();  // next tile ready; everyone done reading cur
    cur ^= 1;
  }
#undef STAGE

  const int rb = bm + (wr << 6) + ((lane >> 4) << 2);
  const int cb = bn + (wc << 6) + (lane & 15);
#pragma unroll
  for (int m = 0; m < 4; ++m) {
#pragma unroll
    for (int n = 0; n < 4; ++n) {
      int col = cb + (n << 4);
#pragma unroll
      for (int j = 0; j < 4; ++j) {
        size_t idx = (size_t)(rb + (m << 4) + j) * N + col;
        float v = acc[m][n][j];
        if (ACC) v += C[idx];
        if (WF32) C[idx] = v;
        if (WBF16) Cb[idx] = f2bf(v);
      }
    }
  }
}

// ---------------------------------------------------------------------------
// LayerNorm over DT=512 per row; writes bf16 q_txt
// ---------------------------------------------------------------------------
__global__ __launch_bounds__(256) void ln_kernel(
    const float* __restrict__ m, const float* __restrict__ g,
    const float* __restrict__ bta, u16* __restrict__ q) {
  int row = blockIdx.x;
  int tid = threadIdx.x;
  float v0 = m[(size_t)row * 512 + tid];
  float v1 = m[(size_t)row * 512 + 256 + tid];
  __shared__ float red[4], red2[4];
  float s = v0 + v1;
#pragma unroll
  for (int d = 32; d; d >>= 1) s += __shfl_xor(s, d);
  if ((tid & 63) == 0) red[tid >> 6] = s;
  __syncthreads();
  float mu = (red[0] + red[1] + red[2] + red[3]) * (1.0f / 512.0f);
  float d0 = v0 - mu, d1 = v1 - mu;
  float s2 = d0 * d0 + d1 * d1;
#pragma unroll
  for (int d = 32; d; d >>= 1) s2 += __shfl_xor(s2, d);
  if ((tid & 63) == 0) red2[tid >> 6] = s2;
  __syncthreads();
  float var = (red2[0] + red2[1] + red2[2] + red2[3]) * (1.0f / 512.0f);
  float r = rsqrtf(var + 1e-5f);
  q[(size_t)row * 512 + tid] = f2bf(d0 * r * g[tid] + bta[tid]);
  q[(size_t)row * 512 + 256 + tid] = f2bf(d1 * r * g[tid + 256] + bta[tid + 256]);
}

// ---------------------------------------------------------------------------
// Banded attention, l-grouped for KV reuse.
// Block = (b, lgroup of 8 l). 4 waves x 2 l each. Register softmax.
// KV: [32768][1024] bf16, cols 0..511 = K, 512..1023 = V.
// ---------------------------------------------------------------------------
__global__ __launch_bounds__(256) void attn_kernel(
    const float* __restrict__ Q, const u16* __restrict__ KV,
    const float* __restrict__ alpha_p, float* __restrict__ A,
    u16* __restrict__ Fv) {
  __shared__ float av_s[8][64];
  const int blk = blockIdx.x;
  const int b = blk >> 5, lg = blk & 31;
  const int tid = threadIdx.x;
  const int w = tid >> 6, lane = tid & 63;
  const float al = *alpha_p;

#pragma unroll
  for (int i = 0; i < 2; ++i) {
    const int wl = w * 2 + i;
    const int l = lg * 8 + wl;
    const int c = (1023 * l) / 255;
    const int lo = max(0, c - BAND_), hi = min(N_ - 1, c + BAND_);
    const int W = hi - lo + 1;  // 17..33
    float qr[8];
    {
      const float4 q1 = *(const float4*)(Q + (size_t)(b * L_ + l) * 512 + lane * 8);
      const float4 q2 = *(const float4*)(Q + (size_t)(b * L_ + l) * 512 + lane * 8 + 4);
      qr[0] = q1.x; qr[1] = q1.y; qr[2] = q1.z; qr[3] = q1.w;
      qr[4] = q2.x; qr[5] = q2.y; qr[6] = q2.z; qr[7] = q2.w;
    }
    float mylogit = 0.f;
    for (int j = 0; j < W; ++j) {
      const u16x8 kv =
          *(const u16x8*)(KV + ((size_t)(b * N_ + lo + j)) * 1024 + lane * 8);
      float s = 0.f;
#pragma unroll
      for (int t = 0; t < 8; ++t) s += bf2f(kv[t]) * qr[t];
#pragma unroll
      for (int d = 32; d; d >>= 1) s += __shfl_xor(s, d);
      mylogit = (lane == j) ? s : mylogit;
    }
    float x = (lane < W)
                  ? mylogit * 0.044194173824159216f +
                        al * ((float)(c - (lo + lane)) * (1.0f / 16.000001f))
                  : -INFINITY;
    float mx = x;
#pragma unroll
    for (int d = 32; d; d >>= 1) mx = fmaxf(mx, __shfl_xor(mx, d));
    float e = (lane < W) ? expf(x - mx) : 0.0f;
    float sm = e;
#pragma unroll
    for (int d = 32; d; d >>= 1) sm += __shfl_xor(sm, d);
    av_s[wl][lane] = (lane < W) ? (e / sm) : 0.0f;
    float* Arow = A + (size_t)(b * L_ + l) * N_;
    for (int p4 = lane; p4 < N_ / 4; p4 += 64) {
      int p = p4 * 4;
      float4 v;
      v.x = (p + 0 >= lo && p + 0 <= hi) ? av_s[wl][p + 0 - lo] : 0.0f;
      v.y = (p + 1 >= lo && p + 1 <= hi) ? av_s[wl][p + 1 - lo] : 0.0f;
      v.z = (p + 2 >= lo && p + 2 <= hi) ? av_s[wl][p + 2 - lo] : 0.0f;
      v.w = (p + 3 >= lo && p + 3 <= hi) ? av_s[wl][p + 3 - lo] : 0.0f;
      ((float4*)Arow)[p4] = v;
    }
    float acc[8] = {};
    for (int j = 0; j < W; ++j) {
      const float avj = av_s[wl][j];
      const u16x8 v =
          *(const u16x8*)(KV + ((size_t)(b * N_ + lo + j)) * 1024 + 512 + lane * 8);
#pragma unroll
      for (int t = 0; t < 8; ++t) acc[t] += avj * bf2f(v[t]);
    }
    u16x8 fo;
#pragma unroll
    for (int t = 0; t < 8; ++t) fo[t] = f2bf(acc[t]);
    *(u16x8*)(Fv + (size_t)(b * L_ + l) * 512 + lane * 8) = fo;
  }
}

// ---------------------------------------------------------------------------
extern "C" void kernel_launch(void* const* d_in, const int* in_sizes, int n_in,
                              void* d_out, int out_size, void* d_ws,
                              size_t ws_size, hipStream_t stream) {
  const float* vis = (const float*)d_in[0];    // [32,1024,512]
  const int* ids = (const int*)d_in[1];        // [32,256,8]
  const float* emb = (const float*)d_in[2];    // [1024,512]
  const float* wq = (const float*)d_in[3];     // [512,512]
  const float* wk = (const float*)d_in[4];     // [512,512]
  const float* wvp = (const float*)d_in[5];    // [512,512]
  const float* wv2t = (const float*)d_in[6];   // [512,512]
  const float* dwk = (const float*)d_in[7];    // [512,1,3]
  const float* pwk = (const float*)d_in[8];    // [512,512,1]
  const float* lng = (const float*)d_in[9];    // [512]
  const float* lnb = (const float*)d_in[10];   // [512]
  const float* alpha = (const float*)d_in[11]; // scalar

  float* out_cls = (float*)d_out;                // [8192,1024]
  float* out_H = out_cls + (size_t)8192 * 1024;  // [8192,512]
  float* out_A = out_H + (size_t)8192 * 512;     // [8192,1024]

  // workspace layout  (~171 MB)
  char* p = (char*)d_ws;
  u16* visb = (u16*)p;              p += (size_t)32768 * 512 * 2;
  u16* KVb  = (u16*)p;              p += (size_t)32768 * 1024 * 2;
  u16* embb = (u16*)p;              p += (size_t)1024 * 512 * 2;
  u16* wqb  = (u16*)p;              p += (size_t)512 * 512 * 2;
  u16* wkvb = (u16*)p;              p += (size_t)1024 * 512 * 2;
  u16* wv2tb= (u16*)p;              p += (size_t)512 * 512 * 2;
  u16* pwkb = (u16*)p;              p += (size_t)512 * 512 * 2;
  u16* shmb = (u16*)p;              p += (size_t)8192 * 512 * 2;
  float* mbuf = (float*)p;          p += (size_t)8192 * 512 * 4;
  u16* qbuf = (u16*)p;              p += (size_t)8192 * 512 * 2;
  float* Qbuf = (float*)p;          p += (size_t)8192 * 512 * 4;
  u16* Fvb  = (u16*)p;              p += (size_t)8192 * 512 * 2;
  u16* Hb   = (u16*)p;              p += (size_t)8192 * 512 * 2;

  // conversions to bf16
  cvt_bf16<<<16384, 256, 0, stream>>>(vis, visb, 32768 * 512 / 4);
  cvt_weights<<<1792, 256, 0, stream>>>(emb, wq, wk, wvp, wv2t, pwk,
                                        embb, wqb, wkvb, wv2tb, pwkb);

  // KV = vis @ [wk;wv]^T  -> bf16 [32768][1024]
  gemm_mfma<false, false, true><<<dim3(8, 256), 256, 0, stream>>>(
      visb, wkvb, nullptr, KVb, 32768, 1024, 512);

  // text front: gather + dwconv + silu + means
  text_front<<<8192, 256, 0, stream>>>(ids, emb, dwk, shmb, mbuf);
  // m += shm_mean @ pw^T  (pointwise conv folded through mean)
  gemm_mfma<true, true, false><<<dim3(4, 64), 256, 0, stream>>>(
      shmb, pwkb, mbuf, nullptr, 8192, 512, 512);
  // LayerNorm -> q_txt (bf16)
  ln_kernel<<<8192, 256, 0, stream>>>(mbuf, lng, lnb, qbuf);
  // Q = q_txt @ wq^T (f32 out)
  gemm_mfma<false, true, false><<<dim3(4, 64), 256, 0, stream>>>(
      qbuf, wqb, Qbuf, nullptr, 8192, 512, 512);
  // banded attention -> A (full rows, f32), Fv (bf16)
  attn_kernel<<<1024, 256, 0, stream>>>(Qbuf, KVb, alpha, out_A, Fvb);
  // H = Fv @ wv2t^T (f32 out + bf16 copy)
  gemm_mfma<false, true, true><<<dim3(4, 64), 256, 0, stream>>>(
      Fvb, wv2tb, out_H, Hb, 8192, 512, 512);
  // cls = H @ emb^T (f32 out)
  gemm_mfma<false, true, false><<<dim3(8, 64), 256, 0, stream>>>(
      Hb, embb, out_cls, nullptr, 8192, 1024, 512);
}